// Round 5
// baseline (202.783 us; speedup 1.0000x reference)
//
#include <hip/hip_runtime.h>
#include <hip/hip_cooperative_groups.h>
#include <cstdint>
#include <cstddef>
#include <math.h>

namespace cg = cooperative_groups;

#define S_LEN  256
#define BATCH  32
#define HID    256
#define EMB    256
#define TSTEPS 10

// Scratch (d_ws) layout — every slot read is plain-stored first, no init:
//   f[0..255]   : block g -> max ||emb[tok]||^2 over its 32 tokens
//                 (batch = g>>3, chunk = g&7)
//   f[256..511] : block g -> ||W1 row g||^2
//   i[512..767] : block g -> Wa1 row g has non-finite entry
//   f[768]      : max b1          (block 0)
//   i[769]      : flags bit0=bad params/b2, bit1=b3 nonzero   (block 0)

__device__ __forceinline__ float wave_sum(float s) {
#pragma unroll
    for (int off = 1; off < 64; off <<= 1) s += __shfl_xor(s, off, 64);
    return s;
}
__device__ __forceinline__ float wave_max(float s) {
#pragma unroll
    for (int off = 1; off < 64; off <<= 1) s = fmaxf(s, __shfl_xor(s, off, 64));
    return s;
}

// ---------------------------------------------------------------------------
// ONE cooperative dispatch. 256 blocks x 256 threads (1 block/CU: grid-wide
// co-residency guaranteed). Phase A: whole-chip stats at round-3 parallelism.
// grid.sync(). Phase B: blocks 0..31 decide + finalize per batch element.
// Silence proof (Cauchy-Schwarz, per batch): max X1 <= max(b1) + maxE*maxW
// < thr1*(1-leak1) => layer 1 never spikes => layer-2 input is exactly b2 =>
// (checked) layer 2 never spikes => acc accumulates exactly b3 per step.
// If additionally b3 == 0 and Wa1 finite: h == +0 exactly, h@Wa1^T == 0
// exactly => out = relu(ba1)@Wa2^T + ba2. Unprovable => exact bit-level
// simulation on wave 0 of block b.
// ---------------------------------------------------------------------------
__global__ __launch_bounds__(256, 1) void snn_coop_kernel(
    const int* __restrict__ text, const float* __restrict__ emb,
    const float* __restrict__ W1, const float* __restrict__ b1,
    const float* __restrict__ W2, const float* __restrict__ b2,
    const float* __restrict__ W3, const float* __restrict__ b3,
    const float* __restrict__ thr1p, const float* __restrict__ leak1p,
    const float* __restrict__ thr2p, const float* __restrict__ leak2p,
    const float* __restrict__ Wa1, const float* __restrict__ ba1,
    const float* __restrict__ Wa2, const float* __restrict__ ba2,
    int* __restrict__ scratch, const int use_ws,
    float* __restrict__ out)
{
    const int g = blockIdx.x;
    const int t = threadIdx.x;
    const int l = t & 63;
    const int w = t >> 6;
    float* scrf = (float*)scratch;

    __shared__ float redA[4], redB[4];
    __shared__ int   redI[4];
    __shared__ int   sdec;
    __shared__ __align__(16) float hsh[HID];
    __shared__ float rsh[HID];
    __shared__ int   stok[S_LEN];

    if (use_ws) {
        // ---- A1: ||W1 row g||^2 (coalesced, 1 float/thread) ----
        const float wv = W1[(size_t)g * EMB + t];
        const float s1 = wave_sum(wv * wv);
        if (l == 0) redA[w] = s1;

        // ---- A2: Wa1 row g finiteness ----
        const float av = Wa1[(size_t)g * HID + t];
        const unsigned long long mnf = __ballot(!isfinite(av));
        if (l == 0) redI[w] = (mnf != 0ULL) ? 1 : 0;

        // ---- A3: emb norms, batch g>>3, tokens (g&7)*32..+31.
        //      8 threads/token, 8 named float4 loads each (ILP=8). ----
        const int b8   = g >> 3;
        const int trow = t >> 3;
        const int p    = t & 7;
        const int tok  = text[((g & 7) * 32 + trow) * BATCH + b8];
        const float4* __restrict__ r =
            (const float4*)(emb + (size_t)tok * EMB) + p * 8;
        const float4 v0 = r[0], v1 = r[1], v2 = r[2], v3 = r[3];
        const float4 v4 = r[4], v5 = r[5], v6 = r[6], v7 = r[7];
        float s = v0.x*v0.x + v0.y*v0.y + v0.z*v0.z + v0.w*v0.w
                + v1.x*v1.x + v1.y*v1.y + v1.z*v1.z + v1.w*v1.w
                + v2.x*v2.x + v2.y*v2.y + v2.z*v2.z + v2.w*v2.w
                + v3.x*v3.x + v3.y*v3.y + v3.z*v3.z + v3.w*v3.w
                + v4.x*v4.x + v4.y*v4.y + v4.z*v4.z + v4.w*v4.w
                + v5.x*v5.x + v5.y*v5.y + v5.z*v5.z + v5.w*v5.w
                + v6.x*v6.x + v6.y*v6.y + v6.z*v6.z + v6.w*v6.w
                + v7.x*v7.x + v7.y*v7.y + v7.z*v7.z + v7.w*v7.w;
#pragma unroll
        for (int off = 1; off < 8; off <<= 1) s += __shfl_xor(s, off, 64);
        s = isnan(s) ? INFINITY : s;
        if (tok == 0) s = 0.f;        // padding row zeroed in the reference
#pragma unroll
        for (int off = 8; off < 64; off <<= 1) s = fmaxf(s, __shfl_xor(s, off, 64));
        if (l == 0) redB[w] = s;
        __syncthreads();
        if (t == 0) {
            const float w2 = redA[0] + redA[1] + redA[2] + redA[3];
            scrf[256 + g] = isnan(w2) ? INFINITY : w2;
            scratch[512 + g] = redI[0] | redI[1] | redI[2] | redI[3];
            scrf[g] = fmaxf(fmaxf(redB[0], redB[1]), fmaxf(redB[2], redB[3]));
        }
        __syncthreads();

        // ---- A4 (block 0): bias / param checks ----
        if (g == 0) {
            const float thr2 = thr2p[0], leak2 = leak2p[0];
            const float c2   = thr2 * (1.0f - leak2) - 1e-4f * thr2 - 1e-6f;
            const float b1i  = b1[t];
            const float b2i  = b2[t];
            const float b3i  = b3[t];
            float mB = isnan(b1i) ? INFINITY : b1i;
            mB = wave_max(mB);
            const bool bad  = !(b2i < c2);                    // catches NaN too
            const bool b3nz = (b3i != 0.0f) || isnan(b3i);
            const unsigned long long mbad = __ballot(bad);
            const unsigned long long mnz  = __ballot(b3nz);
            if (l == 0) {
                redA[w] = mB;
                redI[w] = (mbad ? 1 : 0) | (mnz ? 2 : 0);
            }
            __syncthreads();
            if (t == 0) {
                int f = redI[0] | redI[1] | redI[2] | redI[3];
                const float thr1 = thr1p[0], leak1 = leak1p[0];
                if (!(leak1 >= 0.0f && leak1 < 1.0f &&
                      leak2 >= 0.0f && leak2 < 1.0f &&
                      thr1 > 0.0f && thr2 > 0.0f)) f |= 1;
                scrf[768]    = fmaxf(fmaxf(redA[0], redA[1]),
                                     fmaxf(redA[2], redA[3]));
                scratch[769] = f;
            }
        }
        __threadfence();
    }

    cg::this_grid().sync();

    if (g >= BATCH) return;
    const int b = g;

    // ---- Phase B: reduce stats, decide ----
    bool silent = false, b3anz = true, wa1nf = true;
    if (use_ws) {
        float mw = scrf[256 + t];
        const int nf = scratch[512 + t];
        float me = (t < 8) ? scrf[b * 8 + t] : 0.f;
        mw = wave_max(mw);
        me = wave_max(me);
        const unsigned long long mn = __ballot(nf != 0);
        if (l == 0) {
            redA[w] = mw;
            redB[w] = me;
            redI[w] = (mn != 0ULL) ? 1 : 0;
        }
        __syncthreads();
        if (t == 0) {
            const float maxW2 = fmaxf(fmaxf(redA[0], redA[1]), fmaxf(redA[2], redA[3]));
            const float maxE2 = fmaxf(fmaxf(redB[0], redB[1]), fmaxf(redB[2], redB[3]));
            const int   wnf   = redI[0] | redI[1] | redI[2] | redI[3];
            const float maxb1 = scrf[768];
            const int   flags = scratch[769];
            const float thr1  = thr1p[0], leak1 = leak1p[0];
            const float bound = sqrtf(maxE2 * maxW2) * 1.0001f + maxb1 + 1e-6f;
            const float c1    = thr1 * (1.0f - leak1) - 1e-4f * thr1 - 1e-6f;
            const bool  sil   = ((flags & 1) == 0) && (bound < c1);
            sdec = (sil ? 1 : 0) | (flags & 2) | (wnf ? 4 : 0);
        }
        __syncthreads();
        const int dec = sdec;
        silent = (dec & 1) != 0;
        b3anz  = (dec & 2) != 0;
        wa1nf  = (dec & 4) != 0;
    }

    if (silent && !b3anz && !wa1nf) {
        // ---- fast path: h == +0 exactly, Wa1 finite => h@Wa1^T == 0 ----
        if (w == 0) {
            float q = 0.f;
#pragma unroll
            for (int k = 0; k < 4; ++k) {
                const int i = l + 64 * k;
                q += Wa2[i] * fmaxf(ba1[i], 0.0f);
            }
            q = wave_sum(q);
            if (l == 0) out[b] = q + ba2[0];
        }
        return;                        // block-uniform
    }

    if (silent) {
        // layers silent, b3 != 0: acc = b3 added S*T times in the
        // reference's sequential rounding order.
        const float b3t = b3[t];
        float a = 0.f;
        for (int st = 0; st < S_LEN * TSTEPS; ++st) a += b3t;
        hsh[t] = a * (1.0f / (float)BATCH);
    } else {
        stok[t] = text[t * BATCH + b];
        __syncthreads();
        if (w == 0) {
            // ---- exact in-kernel fallback (wave 0, lane l = neurons l+64k) --
            const float thr1  = thr1p[0],  thr2  = thr2p[0];
            const float leak1 = leak1p[0], leak2 = leak2p[0];
            float b1f[4], b2f[4], b3f[4];
#pragma unroll
            for (int k = 0; k < 4; ++k) {
                b1f[k] = b1[l + 64 * k];
                b2f[k] = b2[l + 64 * k];
                b3f[k] = b3[l + 64 * k];
            }
            float m1[4]  = {0.f, 0.f, 0.f, 0.f};
            float m2[4]  = {0.f, 0.f, 0.f, 0.f};
            float acc[4] = {0.f, 0.f, 0.f, 0.f};

            for (int s = 0; s < S_LEN; ++s) {
                float X1c[4];
                {
                    int tok = stok[s];
                    tok = __builtin_amdgcn_readfirstlane(tok);
                    const float4* __restrict__ xr =
                        (const float4*)(emb + (size_t)tok * EMB);
                    const float sc = (tok == 0) ? 0.0f : 1.0f;
#pragma unroll
                    for (int k = 0; k < 4; ++k) {
                        const float4* __restrict__ wr =
                            (const float4*)(W1 + (size_t)(l + 64 * k) * EMB);
                        float a = 0.f;
                        for (int j4 = 0; j4 < EMB / 4; ++j4) {
                            float4 wv = wr[j4];
                            float4 xv = xr[j4];
                            a += wv.x * xv.x + wv.y * xv.y +
                                 wv.z * xv.z + wv.w * xv.w;
                        }
                        X1c[k] = b1f[k] + sc * a;
                    }
                }

#pragma unroll
                for (int tt = 0; tt < TSTEPS; ++tt) {
                    unsigned long long msk[4];
#pragma unroll
                    for (int k = 0; k < 4; ++k) {
                        m1[k] = fmaf(m1[k], leak1, X1c[k]);
                        const bool sp = m1[k] > thr1;
                        msk[k] = __ballot(sp);
                        m1[k] -= sp ? thr1 : 0.f;
                    }

                    float d2[4] = {b2f[0], b2f[1], b2f[2], b2f[3]};
                    if (msk[0] | msk[1] | msk[2] | msk[3]) {
#pragma unroll
                        for (int k2 = 0; k2 < 4; ++k2) {
                            unsigned long long m = msk[k2];
                            while (m) {
                                const int j = (k2 << 6) + __builtin_ctzll(m);
                                m &= m - 1;
#pragma unroll
                                for (int k = 0; k < 4; ++k)
                                    d2[k] += W2[(size_t)(l + 64 * k) * HID + j];
                            }
                        }
                    }

#pragma unroll
                    for (int k = 0; k < 4; ++k) {
                        m2[k] = fmaf(m2[k], leak2, d2[k]);
                        const bool sp = m2[k] > thr2;
                        msk[k] = __ballot(sp);
                        m2[k] -= sp ? thr2 : 0.f;
                    }

                    float d3[4] = {b3f[0], b3f[1], b3f[2], b3f[3]};
                    if (msk[0] | msk[1] | msk[2] | msk[3]) {
#pragma unroll
                        for (int k2 = 0; k2 < 4; ++k2) {
                            unsigned long long m = msk[k2];
                            while (m) {
                                const int j = (k2 << 6) + __builtin_ctzll(m);
                                m &= m - 1;
#pragma unroll
                                for (int k = 0; k < 4; ++k)
                                    d3[k] += W3[(size_t)(l + 64 * k) * HID + j];
                            }
                        }
                    }
#pragma unroll
                    for (int k = 0; k < 4; ++k) acc[k] += d3[k];
                }
            }
#pragma unroll
            for (int k = 0; k < 4; ++k)
                hsh[l + 64 * k] = acc[k] * (1.0f / (float)BATCH);
        }
    }
    __syncthreads();

    // ---- epilogue: relu(h@Wa1^T + ba1) @ Wa2^T + ba2 (4 waves) ----
    const float4 hv = ((const float4*)hsh)[l];
#pragma unroll 4
    for (int r = w; r < HID; r += 4) {
        const float4 wv = ((const float4*)(Wa1 + (size_t)r * HID))[l];
        const float a = wave_sum(wv.x * hv.x + wv.y * hv.y +
                                 wv.z * hv.z + wv.w * hv.w);
        if (l == 0) rsh[r] = fmaxf(a + ba1[r], 0.0f);
    }
    __syncthreads();

    if (w == 0) {
        float q = 0.f;
#pragma unroll
        for (int k = 0; k < 4; ++k)
            q += Wa2[l + 64 * k] * rsh[l + 64 * k];
        q = wave_sum(q);
        if (l == 0) out[b] = q + ba2[0];
    }
}

// ---------------------------------------------------------------------------
extern "C" void kernel_launch(void* const* d_in, const int* in_sizes, int n_in,
                              void* d_out, int out_size, void* d_ws, size_t ws_size,
                              hipStream_t stream)
{
    const int*   text   = (const int*)  d_in[0];
    // d_in[1] = text_lengths: unused by the reference
    const float* emb    = (const float*)d_in[2];
    const float* W1     = (const float*)d_in[3];
    const float* b1     = (const float*)d_in[4];
    const float* thr1   = (const float*)d_in[5];
    const float* leak1  = (const float*)d_in[6];
    const float* W2     = (const float*)d_in[7];
    const float* b2     = (const float*)d_in[8];
    const float* thr2   = (const float*)d_in[9];
    const float* leak2  = (const float*)d_in[10];
    const float* W3     = (const float*)d_in[11];
    const float* b3     = (const float*)d_in[12];
    const float* Wa1    = (const float*)d_in[13];
    const float* ba1    = (const float*)d_in[14];
    const float* Wa2    = (const float*)d_in[15];
    const float* ba2    = (const float*)d_in[16];
    float*       out    = (float*)d_out;

    int* scratch = (int*)d_ws;
    int  use_ws  = (d_ws != nullptr && ws_size >= 4096) ? 1 : 0;

    void* args[] = {
        (void*)&text, (void*)&emb, (void*)&W1, (void*)&b1,
        (void*)&W2,   (void*)&b2,  (void*)&W3, (void*)&b3,
        (void*)&thr1, (void*)&leak1, (void*)&thr2, (void*)&leak2,
        (void*)&Wa1,  (void*)&ba1, (void*)&Wa2, (void*)&ba2,
        (void*)&scratch, (void*)&use_ws, (void*)&out
    };
    hipLaunchCooperativeKernel((const void*)snn_coop_kernel,
                               dim3(256), dim3(256), args, 0, stream);
}

// Round 6
// 114.835 us; speedup vs baseline: 1.7659x; 1.7659x over previous
//
#include <hip/hip_runtime.h>
#include <cstdint>
#include <cstddef>
#include <math.h>

#define S_LEN  256
#define BATCH  32
#define HID    256
#define EMB    256
#define TSTEPS 10

// Scratch (no init required — every slot K2 reads is plain-stored by K1):
//   f[0..255]   : block g -> max ||emb[tok]||^2 over its 32 tokens
//                 (batch = g>>3, chunk = g&7)
//   f[256..511] : block g -> ||W1 row g||^2
//   i[512..767] : block g -> Wa1 row g has a non-finite entry
//   f[768]      : max b1                                  (block 0)
//   i[769]      : flags bit0=bad params/b2, bit1=b3 != 0  (block 0)
#define SCR_W1   256
#define SCR_WA1  512
#define SCR_B1   768
#define SCR_FLG  769

__device__ __forceinline__ float wave_sum(float s) {
#pragma unroll
    for (int off = 1; off < 64; off <<= 1) s += __shfl_xor(s, off, 64);
    return s;
}
__device__ __forceinline__ float wave_max(float s) {
#pragma unroll
    for (int off = 1; off < 64; off <<= 1) s = fmaxf(s, __shfl_xor(s, off, 64));
    return s;
}

// ---------------------------------------------------------------------------
// Kernel 1: whole-chip stats, 256 blocks x 256 threads (one block per CU).
// Block g does ALL of:
//   - emb-row norms for batch g>>3, tokens (g&7)*32..+31 (8 threads/token,
//     128 B contiguous per thread = 8 independent float4 loads; one vmem
//     instr per wave touches 64 distinct lines, every line fully consumed)
//   - ||W1 row g||^2               (1 float/thread, coalesced)
//   - Wa1 row g finiteness         (1 float/thread, coalesced)
//   - block 0 only: bias/param checks
// Per-block private slots -> no atomics, no memset dispatch.
// ---------------------------------------------------------------------------
__global__ __launch_bounds__(256) void gather_stats_kernel(
    const int* __restrict__ text, const float* __restrict__ emb,
    const float* __restrict__ W1, const float* __restrict__ b1,
    const float* __restrict__ b2, const float* __restrict__ b3,
    const float* __restrict__ Wa1,
    const float* __restrict__ thr1p, const float* __restrict__ leak1p,
    const float* __restrict__ thr2p, const float* __restrict__ leak2p,
    int* __restrict__ scratch)
{
    const int g = blockIdx.x;
    const int t = threadIdx.x;
    const int l = t & 63;
    const int w = t >> 6;
    float* scrf = (float*)scratch;

    __shared__ float redE[4], redW[4];
    __shared__ int   redI[4];

    // ---- W1 row g norm (issue loads first; 1 float/thread) ----
    const float wv = W1[(size_t)g * EMB + t];
    // ---- Wa1 row g finiteness ----
    const float av = Wa1[(size_t)g * HID + t];
    // ---- emb gather: 8 threads/token, 8 float4 each (named => ILP 8) ----
    const int b8   = g >> 3;
    const int trow = t >> 3;
    const int p    = t & 7;
    const int tok  = text[((g & 7) * 32 + trow) * BATCH + b8];
    const float4* __restrict__ r =
        (const float4*)(emb + (size_t)tok * EMB) + p * 8;
    const float4 v0 = r[0], v1 = r[1], v2 = r[2], v3 = r[3];
    const float4 v4 = r[4], v5 = r[5], v6 = r[6], v7 = r[7];

    const float s1 = wave_sum(wv * wv);
    const unsigned long long mnf = __ballot(!isfinite(av));

    float s = v0.x*v0.x + v0.y*v0.y + v0.z*v0.z + v0.w*v0.w
            + v1.x*v1.x + v1.y*v1.y + v1.z*v1.z + v1.w*v1.w
            + v2.x*v2.x + v2.y*v2.y + v2.z*v2.z + v2.w*v2.w
            + v3.x*v3.x + v3.y*v3.y + v3.z*v3.z + v3.w*v3.w
            + v4.x*v4.x + v4.y*v4.y + v4.z*v4.z + v4.w*v4.w
            + v5.x*v5.x + v5.y*v5.y + v5.z*v5.z + v5.w*v5.w
            + v6.x*v6.x + v6.y*v6.y + v6.z*v6.z + v6.w*v6.w
            + v7.x*v7.x + v7.y*v7.y + v7.z*v7.z + v7.w*v7.w;
#pragma unroll
    for (int off = 1; off < 8; off <<= 1) s += __shfl_xor(s, off, 64);
    s = isnan(s) ? INFINITY : s;
    if (tok == 0) s = 0.f;            // padding row zeroed in the reference
#pragma unroll
    for (int off = 8; off < 64; off <<= 1) s = fmaxf(s, __shfl_xor(s, off, 64));

    if (l == 0) {
        redE[w] = s;
        redW[w] = s1;
        redI[w] = (mnf != 0ULL) ? 1 : 0;
    }
    __syncthreads();
    if (t == 0) {
        const float w2 = redW[0] + redW[1] + redW[2] + redW[3];
        scrf[g]           = fmaxf(fmaxf(redE[0], redE[1]), fmaxf(redE[2], redE[3]));
        scrf[SCR_W1 + g]  = isnan(w2) ? INFINITY : w2;
        scratch[SCR_WA1 + g] = redI[0] | redI[1] | redI[2] | redI[3];
    }

    // ---- block 0: bias / param checks ----
    if (g == 0) {
        const float thr2 = thr2p[0], leak2 = leak2p[0];
        const float c2   = thr2 * (1.0f - leak2) - 1e-4f * thr2 - 1e-6f;
        const float b1i  = b1[t];
        const float b2i  = b2[t];
        const float b3i  = b3[t];
        float mB = wave_max(isnan(b1i) ? INFINITY : b1i);
        const bool bad  = !(b2i < c2);                     // catches NaN too
        const bool b3nz = (b3i != 0.0f) || isnan(b3i);
        const unsigned long long mbad = __ballot(bad);
        const unsigned long long mnz  = __ballot(b3nz);
        __syncthreads();                                   // reuse redW/redI
        if (l == 0) {
            redW[w] = mB;
            redI[w] = (mbad ? 1 : 0) | (mnz ? 2 : 0);
        }
        __syncthreads();
        if (t == 0) {
            int f = redI[0] | redI[1] | redI[2] | redI[3];
            const float thr1 = thr1p[0], leak1 = leak1p[0];
            if (!(leak1 >= 0.0f && leak1 < 1.0f &&
                  leak2 >= 0.0f && leak2 < 1.0f &&
                  thr1 > 0.0f && thr2 > 0.0f)) f |= 1;
            scrf[SCR_B1]     = fmaxf(fmaxf(redW[0], redW[1]),
                                     fmaxf(redW[2], redW[3]));
            scratch[SCR_FLG] = f;
        }
    }
}

// ---------------------------------------------------------------------------
// Kernel 2: decide + finalize. 32 blocks x 256 threads (4 waves).
// Silence proof (Cauchy-Schwarz, per batch element): max X1 <= max(b1) +
// maxE*maxW < thr1*(1-leak1) => layer 1 never spikes => layer-2 input is
// exactly b2 => (checked) layer 2 never spikes => acc accumulates exactly
// b3 per step. If additionally b3 == 0 and Wa1 is finite, h == +0 exactly
// and 0 @ Wa1^T == 0 exactly => out = relu(ba1) @ Wa2^T + ba2 directly.
// If the proof fails, wave 0 runs the exact bit-level simulation.
// ---------------------------------------------------------------------------
__global__ __launch_bounds__(256) void snn_final_kernel(
    const int* __restrict__ text, const float* __restrict__ emb,
    const float* __restrict__ W1, const float* __restrict__ b1,
    const float* __restrict__ W2, const float* __restrict__ b2,
    const float* __restrict__ W3, const float* __restrict__ b3,
    const float* __restrict__ thr1p, const float* __restrict__ leak1p,
    const float* __restrict__ thr2p, const float* __restrict__ leak2p,
    const float* __restrict__ Wa1, const float* __restrict__ ba1,
    const float* __restrict__ Wa2, const float* __restrict__ ba2,
    const int* __restrict__ scratch, const int forceExact,
    float* __restrict__ out)
{
    const int b = blockIdx.x;
    const int t = threadIdx.x;
    const int l = t & 63;
    const int w = t >> 6;

    __shared__ __align__(16) float hsh[HID];
    __shared__ float rsh[HID];
    __shared__ int   stok[S_LEN];
    __shared__ float redA[4], redB[4];
    __shared__ int   redI[4];
    __shared__ int   sdec;

    bool silent = false, b3anz = true, wa1nf = true;
    if (!forceExact) {
        const float* scrf = (const float*)scratch;
        const float mw = wave_max(scrf[SCR_W1 + t]);
        const float me = wave_max((t < 8) ? scrf[b * 8 + t] : 0.f);
        const unsigned long long mn = __ballot(scratch[SCR_WA1 + t] != 0);
        if (l == 0) {
            redA[w] = mw;
            redB[w] = me;
            redI[w] = (mn != 0ULL) ? 1 : 0;
        }
        __syncthreads();
        if (t == 0) {
            const float maxW2 = fmaxf(fmaxf(redA[0], redA[1]), fmaxf(redA[2], redA[3]));
            const float maxE2 = fmaxf(fmaxf(redB[0], redB[1]), fmaxf(redB[2], redB[3]));
            const int   wnf   = redI[0] | redI[1] | redI[2] | redI[3];
            const float maxb1 = ((const float*)scratch)[SCR_B1];
            const int   flags = scratch[SCR_FLG];
            const float thr1  = thr1p[0], leak1 = leak1p[0];
            const float bound = sqrtf(maxE2 * maxW2) * 1.0001f + maxb1 + 1e-6f;
            const float c1    = thr1 * (1.0f - leak1) - 1e-4f * thr1 - 1e-6f;
            const bool  sil   = ((flags & 1) == 0) && (bound < c1);
            sdec = (sil ? 1 : 0) | (flags & 2) | (wnf ? 4 : 0);
        }
        __syncthreads();
        const int dec = sdec;
        silent = (dec & 1) != 0;
        b3anz  = (dec & 2) != 0;
        wa1nf  = (dec & 4) != 0;
    }

    if (silent && !b3anz && !wa1nf) {
        // ---- fast path: h == +0 exactly, Wa1 finite => h@Wa1^T == 0 ----
        if (w == 0) {
            float q = 0.f;
#pragma unroll
            for (int k = 0; k < 4; ++k) {
                const int i = l + 64 * k;
                q += Wa2[i] * fmaxf(ba1[i], 0.0f);
            }
            q = wave_sum(q);
            if (l == 0) out[b] = q + ba2[0];
        }
        return;                        // block-uniform
    }

    if (silent) {
        // layers silent, b3 != 0: acc = b3 added S*T times in the
        // reference's sequential rounding order.
        const float b3t = b3[t];
        float a = 0.f;
        for (int st = 0; st < S_LEN * TSTEPS; ++st) a += b3t;
        hsh[t] = a * (1.0f / (float)BATCH);
    } else {
        stok[t] = text[t * BATCH + b];
        __syncthreads();
        if (w == 0) {
            // ---- exact in-kernel fallback (wave 0, lane l = neurons l+64k) --
            const float thr1  = thr1p[0],  thr2  = thr2p[0];
            const float leak1 = leak1p[0], leak2 = leak2p[0];
            float b1f[4], b2f[4], b3f[4];
#pragma unroll
            for (int k = 0; k < 4; ++k) {
                b1f[k] = b1[l + 64 * k];
                b2f[k] = b2[l + 64 * k];
                b3f[k] = b3[l + 64 * k];
            }
            float m1[4]  = {0.f, 0.f, 0.f, 0.f};
            float m2[4]  = {0.f, 0.f, 0.f, 0.f};
            float acc[4] = {0.f, 0.f, 0.f, 0.f};

            for (int s = 0; s < S_LEN; ++s) {
                float X1c[4];
                {
                    int tok = stok[s];
                    tok = __builtin_amdgcn_readfirstlane(tok);
                    const float4* __restrict__ xr =
                        (const float4*)(emb + (size_t)tok * EMB);
                    const float sc = (tok == 0) ? 0.0f : 1.0f;
#pragma unroll
                    for (int k = 0; k < 4; ++k) {
                        const float4* __restrict__ wr =
                            (const float4*)(W1 + (size_t)(l + 64 * k) * EMB);
                        float a = 0.f;
                        for (int j4 = 0; j4 < EMB / 4; ++j4) {
                            float4 wq = wr[j4];
                            float4 xq = xr[j4];
                            a += wq.x * xq.x + wq.y * xq.y +
                                 wq.z * xq.z + wq.w * xq.w;
                        }
                        X1c[k] = b1f[k] + sc * a;
                    }
                }

#pragma unroll
                for (int tt = 0; tt < TSTEPS; ++tt) {
                    unsigned long long msk[4];
#pragma unroll
                    for (int k = 0; k < 4; ++k) {
                        m1[k] = fmaf(m1[k], leak1, X1c[k]);
                        const bool sp = m1[k] > thr1;
                        msk[k] = __ballot(sp);
                        m1[k] -= sp ? thr1 : 0.f;
                    }

                    float d2[4] = {b2f[0], b2f[1], b2f[2], b2f[3]};
                    if (msk[0] | msk[1] | msk[2] | msk[3]) {
#pragma unroll
                        for (int k2 = 0; k2 < 4; ++k2) {
                            unsigned long long m = msk[k2];
                            while (m) {
                                const int j = (k2 << 6) + __builtin_ctzll(m);
                                m &= m - 1;
#pragma unroll
                                for (int k = 0; k < 4; ++k)
                                    d2[k] += W2[(size_t)(l + 64 * k) * HID + j];
                            }
                        }
                    }

#pragma unroll
                    for (int k = 0; k < 4; ++k) {
                        m2[k] = fmaf(m2[k], leak2, d2[k]);
                        const bool sp = m2[k] > thr2;
                        msk[k] = __ballot(sp);
                        m2[k] -= sp ? thr2 : 0.f;
                    }

                    float d3[4] = {b3f[0], b3f[1], b3f[2], b3f[3]};
                    if (msk[0] | msk[1] | msk[2] | msk[3]) {
#pragma unroll
                        for (int k2 = 0; k2 < 4; ++k2) {
                            unsigned long long m = msk[k2];
                            while (m) {
                                const int j = (k2 << 6) + __builtin_ctzll(m);
                                m &= m - 1;
#pragma unroll
                                for (int k = 0; k < 4; ++k)
                                    d3[k] += W3[(size_t)(l + 64 * k) * HID + j];
                            }
                        }
                    }
#pragma unroll
                    for (int k = 0; k < 4; ++k) acc[k] += d3[k];
                }
            }
#pragma unroll
            for (int k = 0; k < 4; ++k)
                hsh[l + 64 * k] = acc[k] * (1.0f / (float)BATCH);
        }
    }
    __syncthreads();

    // ---- epilogue: relu(h@Wa1^T + ba1) @ Wa2^T + ba2 (4 waves) ----
    const float4 hv = ((const float4*)hsh)[l];
#pragma unroll 4
    for (int rr = w; rr < HID; rr += 4) {
        const float4 wq = ((const float4*)(Wa1 + (size_t)rr * HID))[l];
        const float a = wave_sum(wq.x * hv.x + wq.y * hv.y +
                                 wq.z * hv.z + wq.w * hv.w);
        if (l == 0) rsh[rr] = fmaxf(a + ba1[rr], 0.0f);
    }
    __syncthreads();

    if (w == 0) {
        float q = 0.f;
#pragma unroll
        for (int k = 0; k < 4; ++k)
            q += Wa2[l + 64 * k] * rsh[l + 64 * k];
        q = wave_sum(q);
        if (l == 0) out[b] = q + ba2[0];
    }
}

// ---------------------------------------------------------------------------
extern "C" void kernel_launch(void* const* d_in, const int* in_sizes, int n_in,
                              void* d_out, int out_size, void* d_ws, size_t ws_size,
                              hipStream_t stream)
{
    const int*   text   = (const int*)  d_in[0];
    // d_in[1] = text_lengths: unused by the reference
    const float* emb    = (const float*)d_in[2];
    const float* W1     = (const float*)d_in[3];
    const float* b1     = (const float*)d_in[4];
    const float* thr1   = (const float*)d_in[5];
    const float* leak1  = (const float*)d_in[6];
    const float* W2     = (const float*)d_in[7];
    const float* b2     = (const float*)d_in[8];
    const float* thr2   = (const float*)d_in[9];
    const float* leak2  = (const float*)d_in[10];
    const float* W3     = (const float*)d_in[11];
    const float* b3     = (const float*)d_in[12];
    const float* Wa1    = (const float*)d_in[13];
    const float* ba1    = (const float*)d_in[14];
    const float* Wa2    = (const float*)d_in[15];
    const float* ba2    = (const float*)d_in[16];
    float*       out    = (float*)d_out;

    int* scratch = (int*)d_ws;
    const int have_ws = (d_ws != nullptr && ws_size >= 4096) ? 1 : 0;

    if (have_ws) {
        gather_stats_kernel<<<256, 256, 0, stream>>>(
            text, emb, W1, b1, b2, b3, Wa1,
            thr1, leak1, thr2, leak2, scratch);
    }
    snn_final_kernel<<<BATCH, 256, 0, stream>>>(
        text, emb, W1, b1, W2, b2, W3, b3,
        thr1, leak1, thr2, leak2,
        Wa1, ba1, Wa2, ba2,
        scratch, have_ws ? 0 : 1, out);
}